// Round 7
// baseline (81.764 us; speedup 1.0000x reference)
//
#include <hip/hip_runtime.h>

// MTCNN proposal stage: score threshold + greedy NMS + bbox regression, 96x96.
//
// Validated-exact facts (R1-R6 passed, absmax 0.0):
//  - All boxes 21x21 (area 441), pitch 3/4/3 (period 3). IoU>0.5 <=> inter>294.
//  - Suppression pairs only at 12 offsets {+-1,+-2 axial, +-1 diagonal} with an
//    index%3 geometry rule => pure bit logic, no float IoU.
//  - Greedy NMS == unique fixpoint of monotone 3-state relaxation over the
//    dominance graph (priority = score desc, index asc; ties on negative
//    offsets use >=). In-place bitboard Jacobi is race-benign: decisions are
//    final, so stale reads only delay convergence.
//
// R6 (kept): bbox prefetched into 36 VGPRs/thread; ALL later barriers are
// LDS-only (no vmcnt drain) so the 144 KB stream stays in flight under
// mask-build + rounds; epilogue consumes registers.
// R7 (new): DOUBLE-EVAL per barrier round — each word-thread evaluates,
// write-throughs, re-reads neighbors, evaluates again. Monotone => sound for
// any interleaving; propagates ~2 graph-steps per barrier, ~halving the
// barrier-round count (the dominant serial cost).

namespace {

constexpr int Hh = 96, Ww = 96, Nn = Hh * Ww;   // 9216
constexpr int NW = Nn / 64;                      // 144 words
constexpr float THR_SCORE = 0.6f;
constexpr int NT = 1024;
constexpr int CPT = Nn / NT;                     // 9 cells/thread

typedef float v4a __attribute__((ext_vector_type(4), aligned(4)));

// LDS-only barrier: s_waitcnt lgkmcnt(0) + s_barrier; leaves vmcnt untouched.
__device__ __forceinline__ void lds_barrier() {
  __builtin_amdgcn_fence(__ATOMIC_RELEASE, "workgroup", "local");
  __builtin_amdgcn_s_barrier();
  __builtin_amdgcn_fence(__ATOMIC_ACQUIRE, "workgroup", "local");
}

// Bit b -> flat offset: {-1,+1,-2,+2,-96,+96,-192,+192,-97,-95,+95,+97}
__device__ __forceinline__ unsigned long long shift_b(const unsigned long long w[9], int b) {
  // result bit i (word t) = bitmap bit (64*t + i + OFF[b]); w[j] = W[t-4+j]
  switch (b) {
    case 0:  return (w[4] << 1)  | (w[3] >> 63);   // -1
    case 1:  return (w[4] >> 1)  | (w[5] << 63);   // +1
    case 2:  return (w[4] << 2)  | (w[3] >> 62);   // -2
    case 3:  return (w[4] >> 2)  | (w[5] << 62);   // +2
    case 4:  return (w[3] << 32) | (w[2] >> 32);   // -96
    case 5:  return (w[5] >> 32) | (w[6] << 32);   // +96
    case 6:  return w[1];                          // -192
    case 7:  return w[7];                          // +192
    case 8:  return (w[3] << 33) | (w[2] >> 31);   // -97
    case 9:  return (w[3] << 31) | (w[2] >> 33);   // -95
    case 10: return (w[5] >> 31) | (w[6] << 33);   // +95
    default: return (w[5] >> 33) | (w[6] << 31);   // +97
  }
}

__global__ __launch_bounds__(NT) void mtcnn_kernel(
    const float* __restrict__ cls,
    const float* __restrict__ bbox,
    float* __restrict__ out)
{
  __shared__ float s_sc[Nn];                      // staged scores (whole kernel)
  __shared__ unsigned long long s_D[12][NW];      // dominance bitmaps
  __shared__ unsigned long long s_Up[NW + 8];     // UNDEC, 4 guard words/side
  __shared__ unsigned long long s_Kp[NW + 8];     // KEPT
  __shared__ int s_ch[3];                         // period-3 change flags

  unsigned long long* const U = s_Up + 4;
  unsigned long long* const K = s_Kp + 4;

  const int tid = threadIdx.x;
  const int lane = tid & 63;
  const int OFF[12] = {-1, 1, -2, 2, -Ww, Ww, -2*Ww, 2*Ww, -Ww-1, -Ww+1, Ww-1, Ww+1};

  // ---- Phase 1: stage scores, zero guards/flags ----
  for (int q = tid; q < Nn / 4; q += NT)
    reinterpret_cast<float4*>(s_sc)[q] = reinterpret_cast<const float4*>(cls)[q];
  if (tid < 4) {
    s_Up[tid] = 0ull; s_Kp[tid] = 0ull;
    s_Up[4 + NW + tid] = 0ull; s_Kp[4 + NW + tid] = 0ull;
  }
  if (tid < 3) s_ch[tid] = 0;
  lds_barrier();

  // ---- Prefetch bbox into registers; stays in flight through phase 2+rounds
  v4a bb[CPT];
  {
    const v4a* bbox4 = reinterpret_cast<const v4a*>(bbox);
    #pragma unroll
    for (int i = 0; i < CPT; ++i) bb[i] = bbox4[tid + i * NT];
  }
  __builtin_amdgcn_sched_barrier(0);   // pin issue point; don't sink loads

  // ---- Phase 2: per-cell dominance mask (validated logic) -> ballots ----
  for (int n = tid; n < Nn; n += NT) {
    float si = s_sc[n];
    unsigned int m = 0;
    bool valid = si > THR_SCORE;
    if (valid) {
      int r = n / Ww, c = n - r * Ww;
      int rm = r % 3, cm = c % 3;
      unsigned int geom = (1u << 0) | (1u << 1) | (1u << 4) | (1u << 5);
      if (cm == 1) geom |= 1u << 2;
      if (cm == 2) geom |= 1u << 3;
      if (rm == 1) geom |= 1u << 6;
      if (rm == 2) geom |= 1u << 7;
      if (!(rm == 2 && cm == 2)) geom |= 1u << 8;
      if (!(rm == 2 && cm == 1)) geom |= 1u << 9;
      if (!(rm == 1 && cm == 2)) geom |= 1u << 10;
      if (!(rm == 1 && cm == 1)) geom |= 1u << 11;
      unsigned int inb = 0;
      bool cge1 = c >= 1, cle = c <= Ww - 2, rge1 = r >= 1, rle = r <= Hh - 2;
      if (cge1) inb |= 1u << 0;
      if (cle)  inb |= 1u << 1;
      if (c >= 2)      inb |= 1u << 2;
      if (c <= Ww - 3) inb |= 1u << 3;
      if (rge1) inb |= 1u << 4;
      if (rle)  inb |= 1u << 5;
      if (r >= 2)      inb |= 1u << 6;
      if (r <= Hh - 3) inb |= 1u << 7;
      if (rge1 && cge1) inb |= 1u << 8;
      if (rge1 && cle)  inb |= 1u << 9;
      if (rle && cge1)  inb |= 1u << 10;
      if (rle && cle)   inb |= 1u << 11;
      unsigned int cand = geom & inb;
      #pragma unroll
      for (int b = 0; b < 12; ++b) {
        int j = n + OFF[b];
        j = min(max(j, 0), Nn - 1);
        float sj = s_sc[j];
        bool ge = (b == 0) | (b == 2) | (b == 4) | (b == 6) | (b == 8) | (b == 9);
        bool dom = ge ? (sj >= si) : (sj > si);
        if (((cand >> b) & 1u) && (sj > THR_SCORE) && dom) m |= 1u << b;
      }
    }
    int w = n >> 6;
    #pragma unroll
    for (int b = 0; b < 12; ++b) {
      unsigned long long bb2 = __ballot((m >> b) & 1u);
      if (lane == 0) s_D[b][w] = bb2;
    }
    unsigned long long vb = __ballot(valid);
    if (lane == 0) { U[w] = vb; K[w] = 0ull; }
  }
  lds_barrier();

  // ---- Rounds: bitboard Jacobi, DOUBLE-EVAL per barrier; D + self state in
  //      registers; LDS-only barrier per round (keeps bbox loads in flight).
  const int t = tid;
  unsigned long long regD[12];
  unsigned long long u_self = 0ull, k_self = 0ull;
  if (t < NW) {
    #pragma unroll
    for (int b = 0; b < 12; ++b) regD[b] = s_D[b][t];
    u_self = U[t];
  }

  // One in-place eval; returns true if self state changed (write-through).
  auto eval = [&]() -> bool {
    unsigned long long wu[9], wk[9];
    #pragma unroll
    for (int j = 0; j < 9; ++j) {
      if (j == 4) continue;
      wu[j] = U[t - 4 + j]; wk[j] = K[t - 4 + j];
    }
    wu[4] = u_self; wk[4] = k_self;
    unsigned long long anyK = 0ull, anyU = 0ull;
    #pragma unroll
    for (int b = 0; b < 12; ++b) {
      anyK |= shift_b(wk, b) & regD[b];
      anyU |= shift_b(wu, b) & regD[b];
    }
    unsigned long long u2 = u_self & anyU & ~anyK;
    if (u2 != u_self) {
      k_self |= u_self & ~anyU & ~anyK;
      u_self = u2;
      U[t] = u_self; K[t] = k_self;           // write-through (sole writer)
      return true;
    }
    return false;
  };

  for (int it = 0; it < 3000; ++it) {
    const int f = it % 3;
    if (tid == 0) s_ch[(it + 1) % 3] = 0;       // reset next round's flag
    if (t < NW && u_self) {
      bool ch = eval();                          // eval 1 (Jacobi step)
      if (u_self) ch |= eval();                  // eval 2: re-read neighbors,
                                                 // pick up same-round updates
      if (ch) s_ch[f] = 1;                       // benign race: all store 1
    }
    lds_barrier();
    if (s_ch[f] == 0) break;                    // uniform broadcast read
  }
  // K stable: last K writes precede the final (no-change) round's barrier.

  // ---- Epilogue: per-cell from prefetched registers ----
  #pragma unroll
  for (int i = 0; i < CPT; ++i) {
    int n = tid + i * NT;
    int r = n / Ww, c = n - r * Ww;
    float fc = (float)c, fr = (float)r;
    float x1 = rintf((2.0f * fc) / 0.6f);
    float x2 = rintf((2.0f * fc + 12.0f) / 0.6f);
    float y1 = rintf((2.0f * fr) / 0.6f);
    float y2 = rintf((2.0f * fr + 12.0f) / 0.6f);
    float k = (float)((K[n >> 6] >> (n & 63)) & 1ull);
    v4a reg = bb[i];
    float bw = x2 - x1 + 1.0f, bh = y2 - y1 + 1.0f;
    v4a o;
    o.x = (x1 + reg.x * bw) * k;
    o.y = (y1 + reg.y * bh) * k;
    o.z = (x2 + reg.z * bw) * k;
    o.w = (y2 + reg.w * bh) * k;
    *reinterpret_cast<v4a*>(out + n * 5) = o;
    out[n * 5 + 4] = s_sc[n] * k;
  }
}

} // namespace

extern "C" void kernel_launch(void* const* d_in, const int* in_sizes, int n_in,
                              void* d_out, int out_size, void* d_ws, size_t ws_size,
                              hipStream_t stream) {
  const float* cls  = (const float*)d_in[0];   // (96,96) f32
  const float* bbox = (const float*)d_in[1];   // (96,96,4) f32
  float* out = (float*)d_out;                  // (9216,5) f32
  hipLaunchKernelGGL(mtcnn_kernel, dim3(1), dim3(NT), 0, stream, cls, bbox, out);
}

// Round 8
// 79.198 us; speedup vs baseline: 1.0324x; 1.0324x over previous
//
#include <hip/hip_runtime.h>

// MTCNN proposal stage: score threshold + greedy NMS + bbox regression, 96x96.
//
// Validated-exact facts (R1-R7 passed, absmax 0.0):
//  - All boxes 21x21 (area 441), pitch 3/4/3 (period 3). IoU>0.5 <=> inter>294.
//  - Suppression pairs only at 12 offsets {+-1,+-2 axial, +-1 diagonal} with an
//    index%3 geometry rule => pure bit logic, no float IoU.
//  - Greedy NMS == unique fixpoint of monotone 3-state relaxation over the
//    dominance graph (priority = score desc, index asc; ties on negative
//    offsets use >=). In-place bitboard Jacobi is race-benign.
//
// R6 (kept): bbox prefetched into 36 VGPRs/thread; ALL later barriers are
// LDS-only (no vmcnt drain) so the 144 KB stream stays in flight under
// mask-build + rounds; epilogue consumes registers. ONE dispatch.
// R8 (new, after R7's spill regression: +50KB scratch traffic, VGPR=64):
//  - single eval per round (no body duplication);
//  - sliding-window eval: anyK/anyU accumulated while walking W[t-3..t+3],
//    peak live set ~8 u64 instead of 18 => no spill next to bb[36]+regD[24];
//  - __launch_bounds__(NT,4) pins 16-wave occupancy => 128-VGPR budget;
//  - termination flag checked every 2 rounds (pair-indexed period-3 rotation)
//    halving the dependent flag-read cost; <=1 overshoot round (harmless).

namespace {

constexpr int Hh = 96, Ww = 96, Nn = Hh * Ww;   // 9216
constexpr int NW = Nn / 64;                      // 144 words
constexpr float THR_SCORE = 0.6f;
constexpr int NT = 1024;
constexpr int CPT = Nn / NT;                     // 9 cells/thread

typedef float v4a __attribute__((ext_vector_type(4), aligned(4)));

// LDS-only barrier: s_waitcnt lgkmcnt(0) + s_barrier; leaves vmcnt untouched.
__device__ __forceinline__ void lds_barrier() {
  __builtin_amdgcn_fence(__ATOMIC_RELEASE, "workgroup", "local");
  __builtin_amdgcn_s_barrier();
  __builtin_amdgcn_fence(__ATOMIC_ACQUIRE, "workgroup", "local");
}

__global__ __launch_bounds__(NT, 4) void mtcnn_kernel(
    const float* __restrict__ cls,
    const float* __restrict__ bbox,
    float* __restrict__ out)
{
  __shared__ float s_sc[Nn];                      // staged scores (whole kernel)
  __shared__ unsigned long long s_D[12][NW];      // dominance bitmaps
  __shared__ unsigned long long s_Up[NW + 8];     // UNDEC, 4 guard words/side
  __shared__ unsigned long long s_Kp[NW + 8];     // KEPT
  __shared__ int s_ch[3];                         // period-3 PAIR change flags

  unsigned long long* const U = s_Up + 4;
  unsigned long long* const K = s_Kp + 4;

  const int tid = threadIdx.x;
  const int lane = tid & 63;
  const int OFF[12] = {-1, 1, -2, 2, -Ww, Ww, -2*Ww, 2*Ww, -Ww-1, -Ww+1, Ww-1, Ww+1};

  // ---- Phase 1: stage scores, zero guards/flags ----
  for (int q = tid; q < Nn / 4; q += NT)
    reinterpret_cast<float4*>(s_sc)[q] = reinterpret_cast<const float4*>(cls)[q];
  if (tid < 4) {
    s_Up[tid] = 0ull; s_Kp[tid] = 0ull;
    s_Up[4 + NW + tid] = 0ull; s_Kp[4 + NW + tid] = 0ull;
  }
  if (tid < 3) s_ch[tid] = 0;
  lds_barrier();

  // ---- Prefetch bbox into registers; stays in flight through phase 2+rounds
  v4a bb[CPT];
  {
    const v4a* bbox4 = reinterpret_cast<const v4a*>(bbox);
    #pragma unroll
    for (int i = 0; i < CPT; ++i) bb[i] = bbox4[tid + i * NT];
  }
  __builtin_amdgcn_sched_barrier(0);   // pin issue point; don't sink loads

  // ---- Phase 2: per-cell dominance mask (validated logic) -> ballots ----
  for (int n = tid; n < Nn; n += NT) {
    float si = s_sc[n];
    unsigned int m = 0;
    bool valid = si > THR_SCORE;
    if (valid) {
      int r = n / Ww, c = n - r * Ww;
      int rm = r % 3, cm = c % 3;
      unsigned int geom = (1u << 0) | (1u << 1) | (1u << 4) | (1u << 5);
      if (cm == 1) geom |= 1u << 2;
      if (cm == 2) geom |= 1u << 3;
      if (rm == 1) geom |= 1u << 6;
      if (rm == 2) geom |= 1u << 7;
      if (!(rm == 2 && cm == 2)) geom |= 1u << 8;
      if (!(rm == 2 && cm == 1)) geom |= 1u << 9;
      if (!(rm == 1 && cm == 2)) geom |= 1u << 10;
      if (!(rm == 1 && cm == 1)) geom |= 1u << 11;
      unsigned int inb = 0;
      bool cge1 = c >= 1, cle = c <= Ww - 2, rge1 = r >= 1, rle = r <= Hh - 2;
      if (cge1) inb |= 1u << 0;
      if (cle)  inb |= 1u << 1;
      if (c >= 2)      inb |= 1u << 2;
      if (c <= Ww - 3) inb |= 1u << 3;
      if (rge1) inb |= 1u << 4;
      if (rle)  inb |= 1u << 5;
      if (r >= 2)      inb |= 1u << 6;
      if (r <= Hh - 3) inb |= 1u << 7;
      if (rge1 && cge1) inb |= 1u << 8;
      if (rge1 && cle)  inb |= 1u << 9;
      if (rle && cge1)  inb |= 1u << 10;
      if (rle && cle)   inb |= 1u << 11;
      unsigned int cand = geom & inb;
      #pragma unroll
      for (int b = 0; b < 12; ++b) {
        int j = n + OFF[b];
        j = min(max(j, 0), Nn - 1);
        float sj = s_sc[j];
        bool ge = (b == 0) | (b == 2) | (b == 4) | (b == 6) | (b == 8) | (b == 9);
        bool dom = ge ? (sj >= si) : (sj > si);
        if (((cand >> b) & 1u) && (sj > THR_SCORE) && dom) m |= 1u << b;
      }
    }
    int w = n >> 6;
    #pragma unroll
    for (int b = 0; b < 12; ++b) {
      unsigned long long bb2 = __ballot((m >> b) & 1u);
      if (lane == 0) s_D[b][w] = bb2;
    }
    unsigned long long vb = __ballot(valid);
    if (lane == 0) { U[w] = vb; K[w] = 0ull; }
  }
  lds_barrier();

  // ---- Rounds: bitboard Jacobi; sliding-window eval (register-lean);
  //      LDS-only barrier/round; termination checked every 2 rounds. ----
  const int t = tid;
  unsigned long long regD[12];
  unsigned long long u_self = 0ull, k_self = 0ull;
  if (t < NW) {
    #pragma unroll
    for (int b = 0; b < 12; ++b) regD[b] = s_D[b][t];
    u_self = U[t];
  }

  for (int it = 0; it < 3000; ++it) {
    const int pair = it >> 1;
    if ((it & 1) == 0 && tid == 0) s_ch[(pair + 1) % 3] = 0;  // reset NEXT pair's flag
    if (t < NW && u_self) {
      // Sliding-window accumulate of anyK/anyU over W[t-3..t+3].
      unsigned long long anyU, anyK;
      {
        unsigned long long ua = U[t - 3], ka = K[t - 3];
        anyU = ua & regD[6];                 // b6: OFF -192
        anyK = ka & regD[6];
      }
      {
        unsigned long long ub = U[t - 2], kb = K[t - 2];
        unsigned long long uc = U[t - 1], kc = K[t - 1];
        anyU |= ((uc << 32) | (ub >> 32)) & regD[4];   // -96
        anyK |= ((kc << 32) | (kb >> 32)) & regD[4];
        anyU |= ((uc << 33) | (ub >> 31)) & regD[8];   // -97
        anyK |= ((kc << 33) | (kb >> 31)) & regD[8];
        anyU |= ((uc << 31) | (ub >> 33)) & regD[9];   // -95
        anyK |= ((kc << 31) | (kb >> 33)) & regD[9];
        anyU |= ((u_self << 1) | (uc >> 63)) & regD[0];  // -1
        anyK |= ((k_self << 1) | (kc >> 63)) & regD[0];
        anyU |= ((u_self << 2) | (uc >> 62)) & regD[2];  // -2
        anyK |= ((k_self << 2) | (kc >> 62)) & regD[2];
      }
      {
        unsigned long long ud = U[t + 1], kd = K[t + 1];
        unsigned long long ue = U[t + 2], ke = K[t + 2];
        anyU |= ((u_self >> 1) | (ud << 63)) & regD[1];  // +1
        anyK |= ((k_self >> 1) | (kd << 63)) & regD[1];
        anyU |= ((u_self >> 2) | (ud << 62)) & regD[3];  // +2
        anyK |= ((k_self >> 2) | (kd << 62)) & regD[3];
        anyU |= ((ud >> 32) | (ue << 32)) & regD[5];     // +96
        anyK |= ((kd >> 32) | (ke << 32)) & regD[5];
        anyU |= ((ud >> 31) | (ue << 33)) & regD[10];    // +95
        anyK |= ((kd >> 31) | (ke << 33)) & regD[10];
        anyU |= ((ud >> 33) | (ue << 31)) & regD[11];    // +97
        anyK |= ((kd >> 33) | (ke << 31)) & regD[11];
      }
      {
        unsigned long long uf = U[t + 3], kf = K[t + 3];
        anyU |= uf & regD[7];                // +192
        anyK |= kf & regD[7];
      }
      unsigned long long u2 = u_self & anyU & ~anyK;
      if (u2 != u_self) {
        k_self |= u_self & ~anyU & ~anyK;
        u_self = u2;
        U[t] = u_self; K[t] = k_self;        // write-through (sole writer)
        s_ch[pair % 3] = 1;                  // benign race: all store 1
      }
    }
    lds_barrier();
    if ((it & 1) && s_ch[pair % 3] == 0) break;   // uniform broadcast read
  }
  // K stable: last K writes precede the final (no-change) pair's barrier.

  // ---- Epilogue: per-cell from prefetched registers ----
  #pragma unroll
  for (int i = 0; i < CPT; ++i) {
    int n = tid + i * NT;
    int r = n / Ww, c = n - r * Ww;
    float fc = (float)c, fr = (float)r;
    float x1 = rintf((2.0f * fc) / 0.6f);
    float x2 = rintf((2.0f * fc + 12.0f) / 0.6f);
    float y1 = rintf((2.0f * fr) / 0.6f);
    float y2 = rintf((2.0f * fr + 12.0f) / 0.6f);
    float k = (float)((K[n >> 6] >> (n & 63)) & 1ull);
    v4a reg = bb[i];
    float bw = x2 - x1 + 1.0f, bh = y2 - y1 + 1.0f;
    v4a o;
    o.x = (x1 + reg.x * bw) * k;
    o.y = (y1 + reg.y * bh) * k;
    o.z = (x2 + reg.z * bw) * k;
    o.w = (y2 + reg.w * bh) * k;
    *reinterpret_cast<v4a*>(out + n * 5) = o;
    out[n * 5 + 4] = s_sc[n] * k;
  }
}

} // namespace

extern "C" void kernel_launch(void* const* d_in, const int* in_sizes, int n_in,
                              void* d_out, int out_size, void* d_ws, size_t ws_size,
                              hipStream_t stream) {
  const float* cls  = (const float*)d_in[0];   // (96,96) f32
  const float* bbox = (const float*)d_in[1];   // (96,96,4) f32
  float* out = (float*)d_out;                  // (9216,5) f32
  hipLaunchKernelGGL(mtcnn_kernel, dim3(1), dim3(NT), 0, stream, cls, bbox, out);
}

// Round 9
// 77.440 us; speedup vs baseline: 1.0558x; 1.0227x over previous
//
#include <hip/hip_runtime.h>

// MTCNN proposal stage: score threshold + greedy NMS + bbox regression, 96x96.
//
// Validated-exact facts (R1-R8 passed, absmax 0.0):
//  - All boxes 21x21 (area 441), pitch 3/4/3 (period 3). IoU>0.5 <=> inter>294.
//  - Suppression pairs only at 12 offsets {+-1,+-2 axial, +-1 diagonal} with an
//    index%3 geometry rule => pure bit logic, no float IoU.
//  - Greedy NMS == unique fixpoint of monotone 3-state relaxation over the
//    dominance graph (priority = score desc, index asc; ties on negative
//    offsets use >=). In-place bitboard Jacobi is race-benign; ANY
//    interleaving of final-decision updates is sound (R7 double-eval passed).
//
// Kept: ONE dispatch; bbox prefetched into 36 VGPRs/thread; LDS-only barriers
// (no vmcnt drain) keep the 144 KB stream in flight; register-lean
// sliding-window eval; pair-indexed period-3 termination flags.
// R9: (1) double-eval per barrier round with the LEAN body (R7's regression
// was VGPR spill - FETCH/WRITE excess + VGPR=64 - not semantics): 2 graph
// steps per barrier => ~half the barriers & flag reads. (2) guard rows
// (-1.0f, 2 rows top/bottom) on the staged scores => clamp-free phase 2.

namespace {

constexpr int Hh = 96, Ww = 96, Nn = Hh * Ww;   // 9216
constexpr int NW = Nn / 64;                      // 144 words
constexpr int GUARD = 2 * Ww;                    // 192 floats each side
constexpr float THR_SCORE = 0.6f;
constexpr int NT = 1024;
constexpr int CPT = Nn / NT;                     // 9 cells/thread

typedef float v4a __attribute__((ext_vector_type(4), aligned(4)));

// LDS-only barrier: s_waitcnt lgkmcnt(0) + s_barrier; leaves vmcnt untouched.
__device__ __forceinline__ void lds_barrier() {
  __builtin_amdgcn_fence(__ATOMIC_RELEASE, "workgroup", "local");
  __builtin_amdgcn_s_barrier();
  __builtin_amdgcn_fence(__ATOMIC_ACQUIRE, "workgroup", "local");
}

__global__ __launch_bounds__(NT, 4) void mtcnn_kernel(
    const float* __restrict__ cls,
    const float* __restrict__ bbox,
    float* __restrict__ out)
{
  __shared__ __attribute__((aligned(16))) float s_scp[Nn + 2 * GUARD]; // guarded scores
  __shared__ unsigned long long s_D[12][NW];      // dominance bitmaps
  __shared__ unsigned long long s_Up[NW + 8];     // UNDEC, 4 guard words/side
  __shared__ unsigned long long s_Kp[NW + 8];     // KEPT
  __shared__ int s_ch[3];                         // period-3 PAIR change flags

  float* const sc = s_scp + GUARD;
  unsigned long long* const U = s_Up + 4;
  unsigned long long* const K = s_Kp + 4;

  const int tid = threadIdx.x;
  const int lane = tid & 63;
  const int OFF[12] = {-1, 1, -2, 2, -Ww, Ww, -2*Ww, 2*Ww, -Ww-1, -Ww+1, Ww-1, Ww+1};

  // ---- Phase 1: stage scores, fill guards, zero bitmap guards/flags ----
  for (int q = tid; q < Nn / 4; q += NT)
    reinterpret_cast<v4a*>(sc)[q] = reinterpret_cast<const v4a*>(cls)[q];
  if (tid < GUARD) {                 // -1.0f guards: never pass >0.6 check
    s_scp[tid] = -1.0f;
    s_scp[GUARD + Nn + tid] = -1.0f;
  }
  if (tid < 4) {
    s_Up[tid] = 0ull; s_Kp[tid] = 0ull;
    s_Up[4 + NW + tid] = 0ull; s_Kp[4 + NW + tid] = 0ull;
  }
  if (tid < 3) s_ch[tid] = 0;
  lds_barrier();

  // ---- Prefetch bbox into registers; stays in flight through phase 2+rounds
  v4a bb[CPT];
  {
    const v4a* bbox4 = reinterpret_cast<const v4a*>(bbox);
    #pragma unroll
    for (int i = 0; i < CPT; ++i) bb[i] = bbox4[tid + i * NT];
  }
  __builtin_amdgcn_sched_barrier(0);   // pin issue point; don't sink loads

  // ---- Phase 2: per-cell dominance mask (validated logic; clamp-free) ----
  for (int n = tid; n < Nn; n += NT) {
    float si = sc[n];
    unsigned int m = 0;
    bool valid = si > THR_SCORE;
    if (valid) {
      int r = n / Ww, c = n - r * Ww;
      int rm = r % 3, cm = c % 3;
      unsigned int geom = (1u << 0) | (1u << 1) | (1u << 4) | (1u << 5);
      if (cm == 1) geom |= 1u << 2;
      if (cm == 2) geom |= 1u << 3;
      if (rm == 1) geom |= 1u << 6;
      if (rm == 2) geom |= 1u << 7;
      if (!(rm == 2 && cm == 2)) geom |= 1u << 8;
      if (!(rm == 2 && cm == 1)) geom |= 1u << 9;
      if (!(rm == 1 && cm == 2)) geom |= 1u << 10;
      if (!(rm == 1 && cm == 1)) geom |= 1u << 11;
      unsigned int inb = 0;
      bool cge1 = c >= 1, cle = c <= Ww - 2, rge1 = r >= 1, rle = r <= Hh - 2;
      if (cge1) inb |= 1u << 0;
      if (cle)  inb |= 1u << 1;
      if (c >= 2)      inb |= 1u << 2;
      if (c <= Ww - 3) inb |= 1u << 3;
      if (rge1) inb |= 1u << 4;
      if (rle)  inb |= 1u << 5;
      if (r >= 2)      inb |= 1u << 6;
      if (r <= Hh - 3) inb |= 1u << 7;
      if (rge1 && cge1) inb |= 1u << 8;
      if (rge1 && cle)  inb |= 1u << 9;
      if (rle && cge1)  inb |= 1u << 10;
      if (rle && cle)   inb |= 1u << 11;
      unsigned int cand = geom & inb;
      #pragma unroll
      for (int b = 0; b < 12; ++b) {
        float sj = sc[n + OFF[b]];           // guards make this always in-array
        bool ge = (b == 0) | (b == 2) | (b == 4) | (b == 6) | (b == 8) | (b == 9);
        bool dom = ge ? (sj >= si) : (sj > si);
        if (((cand >> b) & 1u) && (sj > THR_SCORE) && dom) m |= 1u << b;
      }
    }
    int w = n >> 6;
    #pragma unroll
    for (int b = 0; b < 12; ++b) {
      unsigned long long bb2 = __ballot((m >> b) & 1u);
      if (lane == 0) s_D[b][w] = bb2;
    }
    unsigned long long vb = __ballot(valid);
    if (lane == 0) { U[w] = vb; K[w] = 0ull; }
  }
  lds_barrier();

  // ---- Rounds: bitboard Jacobi, DOUBLE-EVAL per barrier (lean body);
  //      LDS-only barrier/round; termination checked every 2 rounds. ----
  const int t = tid;
  unsigned long long regD[12];
  unsigned long long u_self = 0ull, k_self = 0ull;
  if (t < NW) {
    #pragma unroll
    for (int b = 0; b < 12; ++b) regD[b] = s_D[b][t];
    u_self = U[t];
  }

  // Register-lean sliding-window eval; write-through on change.
  auto eval = [&]() -> bool {
    unsigned long long anyU, anyK;
    {
      unsigned long long ua = U[t - 3], ka = K[t - 3];
      anyU = ua & regD[6];                 // -192
      anyK = ka & regD[6];
    }
    {
      unsigned long long ub = U[t - 2], kb = K[t - 2];
      unsigned long long uc = U[t - 1], kc = K[t - 1];
      anyU |= ((uc << 32) | (ub >> 32)) & regD[4];   // -96
      anyK |= ((kc << 32) | (kb >> 32)) & regD[4];
      anyU |= ((uc << 33) | (ub >> 31)) & regD[8];   // -97
      anyK |= ((kc << 33) | (kb >> 31)) & regD[8];
      anyU |= ((uc << 31) | (ub >> 33)) & regD[9];   // -95
      anyK |= ((kc << 31) | (kb >> 33)) & regD[9];
      anyU |= ((u_self << 1) | (uc >> 63)) & regD[0];  // -1
      anyK |= ((k_self << 1) | (kc >> 63)) & regD[0];
      anyU |= ((u_self << 2) | (uc >> 62)) & regD[2];  // -2
      anyK |= ((k_self << 2) | (kc >> 62)) & regD[2];
    }
    {
      unsigned long long ud = U[t + 1], kd = K[t + 1];
      unsigned long long ue = U[t + 2], ke = K[t + 2];
      anyU |= ((u_self >> 1) | (ud << 63)) & regD[1];  // +1
      anyK |= ((k_self >> 1) | (kd << 63)) & regD[1];
      anyU |= ((u_self >> 2) | (ud << 62)) & regD[3];  // +2
      anyK |= ((k_self >> 2) | (kd << 62)) & regD[3];
      anyU |= ((ud >> 32) | (ue << 32)) & regD[5];     // +96
      anyK |= ((kd >> 32) | (ke << 32)) & regD[5];
      anyU |= ((ud >> 31) | (ue << 33)) & regD[10];    // +95
      anyK |= ((kd >> 31) | (ke << 33)) & regD[10];
      anyU |= ((ud >> 33) | (ue << 31)) & regD[11];    // +97
      anyK |= ((kd >> 33) | (ke << 31)) & regD[11];
    }
    {
      unsigned long long uf = U[t + 3], kf = K[t + 3];
      anyU |= uf & regD[7];                // +192
      anyK |= kf & regD[7];
    }
    unsigned long long u2 = u_self & anyU & ~anyK;
    if (u2 != u_self) {
      k_self |= u_self & ~anyU & ~anyK;
      u_self = u2;
      U[t] = u_self; K[t] = k_self;        // write-through (sole writer)
      return true;
    }
    return false;
  };

  for (int it = 0; it < 3000; ++it) {
    const int pair = it >> 1;
    if ((it & 1) == 0 && tid == 0) s_ch[(pair + 1) % 3] = 0;  // reset NEXT pair's flag
    if (t < NW && u_self) {
      bool ch = eval();                    // step 1 (Jacobi)
      if (u_self) ch |= eval();            // step 2: picks up same-round updates
      if (ch) s_ch[pair % 3] = 1;          // benign race: all store 1
    }
    lds_barrier();
    if ((it & 1) && s_ch[pair % 3] == 0) break;   // uniform broadcast read
  }
  // K stable: last K writes precede the final (no-change) pair's barrier.

  // ---- Epilogue: per-cell from prefetched registers ----
  #pragma unroll
  for (int i = 0; i < CPT; ++i) {
    int n = tid + i * NT;
    int r = n / Ww, c = n - r * Ww;
    float fc = (float)c, fr = (float)r;
    float x1 = rintf((2.0f * fc) / 0.6f);
    float x2 = rintf((2.0f * fc + 12.0f) / 0.6f);
    float y1 = rintf((2.0f * fr) / 0.6f);
    float y2 = rintf((2.0f * fr + 12.0f) / 0.6f);
    float k = (float)((K[n >> 6] >> (n & 63)) & 1ull);
    v4a reg = bb[i];
    float bw = x2 - x1 + 1.0f, bh = y2 - y1 + 1.0f;
    v4a o;
    o.x = (x1 + reg.x * bw) * k;
    o.y = (y1 + reg.y * bh) * k;
    o.z = (x2 + reg.z * bw) * k;
    o.w = (y2 + reg.w * bh) * k;
    *reinterpret_cast<v4a*>(out + n * 5) = o;
    out[n * 5 + 4] = sc[n] * k;
  }
}

} // namespace

extern "C" void kernel_launch(void* const* d_in, const int* in_sizes, int n_in,
                              void* d_out, int out_size, void* d_ws, size_t ws_size,
                              hipStream_t stream) {
  const float* cls  = (const float*)d_in[0];   // (96,96) f32
  const float* bbox = (const float*)d_in[1];   // (96,96,4) f32
  float* out = (float*)d_out;                  // (9216,5) f32
  hipLaunchKernelGGL(mtcnn_kernel, dim3(1), dim3(NT), 0, stream, cls, bbox, out);
}

// Round 10
// 73.354 us; speedup vs baseline: 1.1146x; 1.0557x over previous
//
#include <hip/hip_runtime.h>

// MTCNN proposal stage: score threshold + greedy NMS + bbox regression, 96x96.
//
// Validated-exact facts (R1-R9 passed, absmax 0.0):
//  - All boxes 21x21 (area 441), pitch 3/4/3 (period 3). IoU>0.5 <=> inter>294.
//  - Suppression pairs only at 12 offsets {+-1,+-2 axial, +-1 diagonal} with an
//    index%3 geometry rule => pure bit logic, no float IoU.
//  - Greedy NMS == unique fixpoint of monotone 3-state relaxation over the
//    dominance graph (priority = score desc, index asc; ties on negative
//    offsets use >=). Bitboard Jacobi with in-place updates is race-benign;
//    any interleaving of final decisions is sound (double-eval validated).
//
// R10: REDUNDANT-NMS MULTI-BLOCK. 9 blocks each compute the full NMS
// fixpoint independently in their own LDS (deterministic => all agree),
// then each block runs the epilogue for its own 1024-cell slice. Redundant
// compute is free across CUs; zero inter-block communication, one dispatch,
// no co-residency assumption. This takes the 324 KB epilogue I/O off the
// single-CU critical path (was ~8 us serial) and shrinks the bbox prefetch
// to one register per thread.
// Kept from R6-R9: LDS-only barriers (no vmcnt drain), guard-row clamp-free
// mask build, register-lean sliding-window eval, double-eval per barrier,
// pair-indexed period-3 termination flags.

namespace {

constexpr int Hh = 96, Ww = 96, Nn = Hh * Ww;   // 9216
constexpr int NW = Nn / 64;                      // 144 words
constexpr int GUARD = 2 * Ww;                    // 192 floats each side
constexpr float THR_SCORE = 0.6f;
constexpr int NT = 1024;
constexpr int NBLK = Nn / NT;                    // 9 blocks, 1 cell/thread each

typedef float v4a __attribute__((ext_vector_type(4), aligned(4)));

// LDS-only barrier: s_waitcnt lgkmcnt(0) + s_barrier; leaves vmcnt untouched.
__device__ __forceinline__ void lds_barrier() {
  __builtin_amdgcn_fence(__ATOMIC_RELEASE, "workgroup", "local");
  __builtin_amdgcn_s_barrier();
  __builtin_amdgcn_fence(__ATOMIC_ACQUIRE, "workgroup", "local");
}

__global__ __launch_bounds__(NT, 4) void mtcnn_kernel(
    const float* __restrict__ cls,
    const float* __restrict__ bbox,
    float* __restrict__ out)
{
  __shared__ __attribute__((aligned(16))) float s_scp[Nn + 2 * GUARD]; // guarded scores
  __shared__ unsigned long long s_D[12][NW];      // dominance bitmaps
  __shared__ unsigned long long s_Up[NW + 8];     // UNDEC, 4 guard words/side
  __shared__ unsigned long long s_Kp[NW + 8];     // KEPT
  __shared__ int s_ch[3];                         // period-3 PAIR change flags

  float* const sc = s_scp + GUARD;
  unsigned long long* const U = s_Up + 4;
  unsigned long long* const K = s_Kp + 4;

  const int tid = threadIdx.x;
  const int lane = tid & 63;
  const int OFF[12] = {-1, 1, -2, 2, -Ww, Ww, -2*Ww, 2*Ww, -Ww-1, -Ww+1, Ww-1, Ww+1};

  // ---- Phase 1: stage scores, fill guards, zero bitmap guards/flags ----
  for (int q = tid; q < Nn / 4; q += NT)
    reinterpret_cast<v4a*>(sc)[q] = reinterpret_cast<const v4a*>(cls)[q];
  if (tid < GUARD) {                 // -1.0f guards: never pass >0.6 check
    s_scp[tid] = -1.0f;
    s_scp[GUARD + Nn + tid] = -1.0f;
  }
  if (tid < 4) {
    s_Up[tid] = 0ull; s_Kp[tid] = 0ull;
    s_Up[4 + NW + tid] = 0ull; s_Kp[4 + NW + tid] = 0ull;
  }
  if (tid < 3) s_ch[tid] = 0;
  lds_barrier();

  // ---- Prefetch THIS BLOCK'S bbox cell; in flight through phase 2+rounds
  const int ncell = blockIdx.x * NT + tid;        // this thread's epilogue cell
  v4a bb0 = reinterpret_cast<const v4a*>(bbox)[ncell];
  __builtin_amdgcn_sched_barrier(0);   // pin issue point; don't sink the load

  // ---- Phase 2: per-cell dominance mask (validated logic; clamp-free) ----
  for (int n = tid; n < Nn; n += NT) {
    float si = sc[n];
    unsigned int m = 0;
    bool valid = si > THR_SCORE;
    if (valid) {
      int r = n / Ww, c = n - r * Ww;
      int rm = r % 3, cm = c % 3;
      unsigned int geom = (1u << 0) | (1u << 1) | (1u << 4) | (1u << 5);
      if (cm == 1) geom |= 1u << 2;
      if (cm == 2) geom |= 1u << 3;
      if (rm == 1) geom |= 1u << 6;
      if (rm == 2) geom |= 1u << 7;
      if (!(rm == 2 && cm == 2)) geom |= 1u << 8;
      if (!(rm == 2 && cm == 1)) geom |= 1u << 9;
      if (!(rm == 1 && cm == 2)) geom |= 1u << 10;
      if (!(rm == 1 && cm == 1)) geom |= 1u << 11;
      unsigned int inb = 0;
      bool cge1 = c >= 1, cle = c <= Ww - 2, rge1 = r >= 1, rle = r <= Hh - 2;
      if (cge1) inb |= 1u << 0;
      if (cle)  inb |= 1u << 1;
      if (c >= 2)      inb |= 1u << 2;
      if (c <= Ww - 3) inb |= 1u << 3;
      if (rge1) inb |= 1u << 4;
      if (rle)  inb |= 1u << 5;
      if (r >= 2)      inb |= 1u << 6;
      if (r <= Hh - 3) inb |= 1u << 7;
      if (rge1 && cge1) inb |= 1u << 8;
      if (rge1 && cle)  inb |= 1u << 9;
      if (rle && cge1)  inb |= 1u << 10;
      if (rle && cle)   inb |= 1u << 11;
      unsigned int cand = geom & inb;
      #pragma unroll
      for (int b = 0; b < 12; ++b) {
        float sj = sc[n + OFF[b]];           // guards make this always in-array
        bool ge = (b == 0) | (b == 2) | (b == 4) | (b == 6) | (b == 8) | (b == 9);
        bool dom = ge ? (sj >= si) : (sj > si);
        if (((cand >> b) & 1u) && (sj > THR_SCORE) && dom) m |= 1u << b;
      }
    }
    int w = n >> 6;
    #pragma unroll
    for (int b = 0; b < 12; ++b) {
      unsigned long long bb2 = __ballot((m >> b) & 1u);
      if (lane == 0) s_D[b][w] = bb2;
    }
    unsigned long long vb = __ballot(valid);
    if (lane == 0) { U[w] = vb; K[w] = 0ull; }
  }
  lds_barrier();

  // ---- Rounds: bitboard Jacobi, DOUBLE-EVAL per barrier (lean body);
  //      LDS-only barrier/round; termination checked every 2 rounds. ----
  const int t = tid;
  unsigned long long regD[12];
  unsigned long long u_self = 0ull, k_self = 0ull;
  if (t < NW) {
    #pragma unroll
    for (int b = 0; b < 12; ++b) regD[b] = s_D[b][t];
    u_self = U[t];
  }

  // Register-lean sliding-window eval; write-through on change.
  auto eval = [&]() -> bool {
    unsigned long long anyU, anyK;
    {
      unsigned long long ua = U[t - 3], ka = K[t - 3];
      anyU = ua & regD[6];                 // -192
      anyK = ka & regD[6];
    }
    {
      unsigned long long ub = U[t - 2], kb = K[t - 2];
      unsigned long long uc = U[t - 1], kc = K[t - 1];
      anyU |= ((uc << 32) | (ub >> 32)) & regD[4];   // -96
      anyK |= ((kc << 32) | (kb >> 32)) & regD[4];
      anyU |= ((uc << 33) | (ub >> 31)) & regD[8];   // -97
      anyK |= ((kc << 33) | (kb >> 31)) & regD[8];
      anyU |= ((uc << 31) | (ub >> 33)) & regD[9];   // -95
      anyK |= ((kc << 31) | (kb >> 33)) & regD[9];
      anyU |= ((u_self << 1) | (uc >> 63)) & regD[0];  // -1
      anyK |= ((k_self << 1) | (kc >> 63)) & regD[0];
      anyU |= ((u_self << 2) | (uc >> 62)) & regD[2];  // -2
      anyK |= ((k_self << 2) | (kc >> 62)) & regD[2];
    }
    {
      unsigned long long ud = U[t + 1], kd = K[t + 1];
      unsigned long long ue = U[t + 2], ke = K[t + 2];
      anyU |= ((u_self >> 1) | (ud << 63)) & regD[1];  // +1
      anyK |= ((k_self >> 1) | (kd << 63)) & regD[1];
      anyU |= ((u_self >> 2) | (ud << 62)) & regD[3];  // +2
      anyK |= ((k_self >> 2) | (kd << 62)) & regD[3];
      anyU |= ((ud >> 32) | (ue << 32)) & regD[5];     // +96
      anyK |= ((kd >> 32) | (ke << 32)) & regD[5];
      anyU |= ((ud >> 31) | (ue << 33)) & regD[10];    // +95
      anyK |= ((kd >> 31) | (ke << 33)) & regD[10];
      anyU |= ((ud >> 33) | (ue << 31)) & regD[11];    // +97
      anyK |= ((kd >> 33) | (ke << 31)) & regD[11];
    }
    {
      unsigned long long uf = U[t + 3], kf = K[t + 3];
      anyU |= uf & regD[7];                // +192
      anyK |= kf & regD[7];
    }
    unsigned long long u2 = u_self & anyU & ~anyK;
    if (u2 != u_self) {
      k_self |= u_self & ~anyU & ~anyK;
      u_self = u2;
      U[t] = u_self; K[t] = k_self;        // write-through (sole writer)
      return true;
    }
    return false;
  };

  for (int it = 0; it < 3000; ++it) {
    const int pair = it >> 1;
    if ((it & 1) == 0 && tid == 0) s_ch[(pair + 1) % 3] = 0;  // reset NEXT pair's flag
    if (t < NW && u_self) {
      bool ch = eval();                    // step 1 (Jacobi)
      if (u_self) ch |= eval();            // step 2: picks up same-round updates
      if (ch) s_ch[pair % 3] = 1;          // benign race: all store 1
    }
    lds_barrier();
    if ((it & 1) && s_ch[pair % 3] == 0) break;   // uniform broadcast read
  }
  // K stable: last K writes precede the final (no-change) pair's barrier.

  // ---- Epilogue: this block's 1024-cell slice, from the prefetched reg ----
  {
    const int n = ncell;
    int r = n / Ww, c = n - r * Ww;
    float fc = (float)c, fr = (float)r;
    float x1 = rintf((2.0f * fc) / 0.6f);
    float x2 = rintf((2.0f * fc + 12.0f) / 0.6f);
    float y1 = rintf((2.0f * fr) / 0.6f);
    float y2 = rintf((2.0f * fr + 12.0f) / 0.6f);
    float k = (float)((K[n >> 6] >> (n & 63)) & 1ull);
    float bw = x2 - x1 + 1.0f, bh = y2 - y1 + 1.0f;
    v4a o;
    o.x = (x1 + bb0.x * bw) * k;
    o.y = (y1 + bb0.y * bh) * k;
    o.z = (x2 + bb0.z * bw) * k;
    o.w = (y2 + bb0.w * bh) * k;
    *reinterpret_cast<v4a*>(out + n * 5) = o;
    out[n * 5 + 4] = sc[n] * k;
  }
}

} // namespace

extern "C" void kernel_launch(void* const* d_in, const int* in_sizes, int n_in,
                              void* d_out, int out_size, void* d_ws, size_t ws_size,
                              hipStream_t stream) {
  const float* cls  = (const float*)d_in[0];   // (96,96) f32
  const float* bbox = (const float*)d_in[1];   // (96,96,4) f32
  float* out = (float*)d_out;                  // (9216,5) f32
  hipLaunchKernelGGL(mtcnn_kernel, dim3(NBLK), dim3(NT), 0, stream,
                     cls, bbox, out);
}